// Round 5
// baseline (769.328 us; speedup 1.0000x reference)
//
#include <hip/hip_runtime.h>
#include <math.h>

#define C_   512
#define C8_  64
#define HH   96
#define WW   96
#define PP   9216            // HH*WW
#define CP   4718592         // C_*PP
#define C8P  589824          // C8_*PP
#define ATTN 1769472         // PP*192

typedef __attribute__((ext_vector_type(4))) float f32x4;
typedef __attribute__((ext_vector_type(8))) __bf16 bf16x8;
typedef __attribute__((ext_vector_type(8))) unsigned short ushort8;
typedef __attribute__((ext_vector_type(4))) unsigned short ushort4v;

__device__ __forceinline__ float bf2f(unsigned short u) {
    union { unsigned u; float f; } x; x.u = ((unsigned)u) << 16; return x.f;
}
__device__ __forceinline__ unsigned short f2bf(float f) {
    union { float f; unsigned u; } x; x.f = f;
    unsigned r = x.u + 0x7fffu + ((x.u >> 16) & 1u);
    return (unsigned short)(r >> 16);
}
__device__ __forceinline__ void gload16(const void* g, void* l) {
    __builtin_amdgcn_global_load_lds(
        (const __attribute__((address_space(1))) unsigned int*)g,
        (__attribute__((address_space(3))) unsigned int*)l, 16, 0, 0);
}

// ---------------- all 4 weight casts in one dispatch, float4-wide ----------------
__global__ __launch_bounds__(256) void cast_w(
    const float* __restrict__ Wv, const float* __restrict__ Wqv,
    const float* __restrict__ Wq, const float* __restrict__ Wk,
    unsigned short* __restrict__ oV, unsigned short* __restrict__ oQV,
    unsigned short* __restrict__ oQ, unsigned short* __restrict__ oK)
{
    int y = blockIdx.y;
    int n = (y < 2) ? 262144 : 32768;
    const float* s = (y == 0) ? Wv : (y == 1) ? Wqv : (y == 2) ? Wq : Wk;
    unsigned short* d = (y == 0) ? oV : (y == 1) ? oQV : (y == 2) ? oQ : oK;
    int i = (blockIdx.x * 256 + threadIdx.x) * 4;
    if (i < n) {
        float4 v = *(const float4*)(s + i);
        ushort4v o = { f2bf(v.x), f2bf(v.y), f2bf(v.z), f2bf(v.w) };
        *(ushort4v*)(d + i) = o;
    }
}

// ---------------- x [C][P] fp32 -> xT [P][C] bf16, both tensors, vectorized ----------------
// grid (144, 8, 2g): z = (b<<1)|which
__global__ __launch_bounds__(256) void cast_transpose_cp(
    const float* __restrict__ xq, const float* __restrict__ xe,
    unsigned short* __restrict__ xTq, unsigned short* __restrict__ xTe)
{
    int zz = blockIdx.z;
    int which = zz & 1;
    size_t b = zz >> 1;
    const float* xb = (which ? xe : xq) + b * (size_t)CP;
    unsigned short* xTb = (which ? xTe : xTq) + b * (size_t)CP;
    int p0 = blockIdx.x * 64, c0 = blockIdx.y * 64;

    __shared__ __align__(16) unsigned short T[64][72];   // [p][c]
    int t = threadIdx.x;
    int cg = t >> 4, pc = t & 15;
#pragma unroll
    for (int i = 0; i < 4; ++i) {
        int c = cg + 16 * i;
        float4 v = *(const float4*)(xb + (size_t)(c0 + c) * PP + p0 + pc * 4);
        T[pc * 4 + 0][c] = f2bf(v.x);
        T[pc * 4 + 1][c] = f2bf(v.y);
        T[pc * 4 + 2][c] = f2bf(v.z);
        T[pc * 4 + 3][c] = f2bf(v.w);
    }
    __syncthreads();
    int pr = t >> 3, ch = t & 7;
#pragma unroll
    for (int i = 0; i < 2; ++i) {
        int p = pr + 32 * i;
        ushort8 u = *(const ushort8*)&T[p][ch * 8];
        *(ushort8*)(xTb + (size_t)(p0 + p) * C_ + c0 + ch * 8) = u;
    }
}

// ---------------- MFMA GEMM q & k (BM=64, fp32 out): grid (72, 2, g) ----------------
__global__ __launch_bounds__(256) void gemm_qk(
    const unsigned short* __restrict__ Wqb, const unsigned short* __restrict__ Wkb,
    const unsigned short* __restrict__ xTq, const unsigned short* __restrict__ xTe,
    const float* __restrict__ bq, const float* __restrict__ bk,
    float* __restrict__ qout, float* __restrict__ kout)
{
    int sel = blockIdx.y;
    const unsigned short* A = sel ? Wkb : Wqb;
    const float* bias = sel ? bk : bq;
    int p0 = blockIdx.x * 128;
    size_t b = blockIdx.z;
    const unsigned short* Bb = (sel ? xTe : xTq) + b * (size_t)CP;
    float* outb = (sel ? kout : qout) + b * (size_t)C8P;

    __shared__ __align__(16) unsigned short Asm[64 * 32];
    __shared__ __align__(16) unsigned short Bsm[128 * 32];

    int tid = threadIdx.x;
    int lane = tid & 63, wid = tid >> 6;
    int wr = wid >> 1, wc = wid & 1;
    int l15 = lane & 15, l4 = lane >> 4;
    f32x4 acc[2][4] = {};

    for (int k0 = 0; k0 < 512; k0 += 32) {
        int c = tid;
        gload16(A + (size_t)(c >> 2) * 512 + k0 + (c & 3) * 8, Asm + c * 8);
        gload16(Bb + (size_t)(p0 + (c >> 2)) * 512 + k0 + (c & 3) * 8, Bsm + c * 8);
        int cb = tid + 256;
        gload16(Bb + (size_t)(p0 + (cb >> 2)) * 512 + k0 + (cb & 3) * 8, Bsm + cb * 8);
        __syncthreads();
        bf16x8 af[2], bfr[4];
#pragma unroll
        for (int m = 0; m < 2; ++m)
            af[m] = *(const bf16x8*)&Asm[(wr * 32 + m * 16 + l15) * 32 + l4 * 8];
#pragma unroll
        for (int n = 0; n < 4; ++n)
            bfr[n] = *(const bf16x8*)&Bsm[(wc * 64 + n * 16 + l15) * 32 + l4 * 8];
#pragma unroll
        for (int m = 0; m < 2; ++m)
#pragma unroll
            for (int n = 0; n < 4; ++n)
                acc[m][n] = __builtin_amdgcn_mfma_f32_16x16x32_bf16(af[m], bfr[n], acc[m][n], 0, 0, 0);
        __syncthreads();
    }
#pragma unroll
    for (int m = 0; m < 2; ++m)
#pragma unroll
        for (int n = 0; n < 4; ++n) {
            int pcol = p0 + wc * 64 + n * 16 + l15;
#pragma unroll
            for (int r = 0; r < 4; ++r) {
                int orow = wr * 32 + m * 16 + l4 * 4 + r;
                outb[(size_t)orow * PP + pcol] = acc[m][n][r] + bias[orow];
            }
        }
}

// ---------------- MFMA GEMM v/qv (BM=128, bf16 out): grid (72, 4, g) ----------------
__global__ __launch_bounds__(256) void gemm_v(
    const unsigned short* __restrict__ A, const unsigned short* __restrict__ Bmat,
    const float* __restrict__ bias, unsigned short* __restrict__ outb)
{
    int p0 = blockIdx.x * 128;
    int o0 = blockIdx.y * 128;
    size_t b = blockIdx.z;
    const unsigned short* Bb = Bmat + b * (size_t)CP;
    unsigned short* ob = outb + b * (size_t)CP;

    __shared__ __align__(16) unsigned short Asm[128 * 32];
    __shared__ __align__(16) unsigned short Bsm[128 * 32];

    int tid = threadIdx.x;
    int lane = tid & 63, wid = tid >> 6;
    int wr = wid >> 1, wc = wid & 1;
    int l15 = lane & 15, l4 = lane >> 4;
    f32x4 acc[4][4] = {};

    for (int k0 = 0; k0 < 512; k0 += 32) {
        int c = tid;
        gload16(A + (size_t)(o0 + (c >> 2)) * 512 + k0 + (c & 3) * 8, Asm + c * 8);
        int ca = tid + 256;
        gload16(A + (size_t)(o0 + (ca >> 2)) * 512 + k0 + (ca & 3) * 8, Asm + ca * 8);
        gload16(Bb + (size_t)(p0 + (c >> 2)) * 512 + k0 + (c & 3) * 8, Bsm + c * 8);
        int cb = tid + 256;
        gload16(Bb + (size_t)(p0 + (cb >> 2)) * 512 + k0 + (cb & 3) * 8, Bsm + cb * 8);
        __syncthreads();
        bf16x8 af[4], bfr[4];
#pragma unroll
        for (int m = 0; m < 4; ++m)
            af[m] = *(const bf16x8*)&Asm[(wr * 64 + m * 16 + l15) * 32 + l4 * 8];
#pragma unroll
        for (int n = 0; n < 4; ++n)
            bfr[n] = *(const bf16x8*)&Bsm[(wc * 64 + n * 16 + l15) * 32 + l4 * 8];
#pragma unroll
        for (int m = 0; m < 4; ++m)
#pragma unroll
            for (int n = 0; n < 4; ++n)
                acc[m][n] = __builtin_amdgcn_mfma_f32_16x16x32_bf16(af[m], bfr[n], acc[m][n], 0, 0, 0);
        __syncthreads();
    }
#pragma unroll
    for (int m = 0; m < 4; ++m)
#pragma unroll
        for (int n = 0; n < 4; ++n) {
            int pcol = p0 + wc * 64 + n * 16 + l15;
#pragma unroll
            for (int r = 0; r < 4; ++r) {
                int orow = o0 + wr * 64 + m * 16 + l4 * 4 + r;
                ob[(size_t)orow * PP + pcol] = f2bf(acc[m][n][r] + bias[orow]);
            }
        }
}

// ---------------- spatial transpose fp32 q & k, vectorized: grid (2*g*64) ----------------
__global__ __launch_bounds__(256) void transpose_hw_qk(
    const float* __restrict__ q, const float* __restrict__ k,
    float* __restrict__ qT, float* __restrict__ kT, int nimg)
{
    int mm = blockIdx.x;
    const float* im; float* om;
    if (mm < nimg) { im = q + (size_t)mm * PP; om = qT + (size_t)mm * PP; }
    else { im = k + (size_t)(mm - nimg) * PP; om = kT + (size_t)(mm - nimg) * PP; }

    __shared__ __align__(16) float T[96][100];
    int t = threadIdx.x;
    for (int v = t; v < 96 * 24; v += 256) {
        int r = v / 24, ch = v - r * 24;
        *(float4*)&T[r][ch * 4] = *(const float4*)(im + r * 96 + ch * 4);
    }
    __syncthreads();
    for (int v = t; v < 96 * 24; v += 256) {
        int r = v / 24, ch = v - r * 24;
        float4 o;
        o.x = T[ch * 4 + 0][r]; o.y = T[ch * 4 + 1][r];
        o.z = T[ch * 4 + 2][r]; o.w = T[ch * 4 + 3][r];
        *(float4*)(om + r * 96 + ch * 4) = o;
    }
}

// ---------------- spatial transpose bf16 (v -> vT), vectorized: grid (g*512) ----------------
__global__ __launch_bounds__(256) void transpose_hw_b(
    const unsigned short* __restrict__ in, unsigned short* __restrict__ out)
{
    size_t m = blockIdx.x;
    const unsigned short* im = in + m * (size_t)PP;
    unsigned short* om = out + m * (size_t)PP;
    __shared__ __align__(16) unsigned short T[96][104];
    int t = threadIdx.x;
    for (int v = t; v < 96 * 12; v += 256) {
        int r = v / 12, ch = v - r * 12;
        *(ushort8*)&T[r][ch * 8] = *(const ushort8*)(im + r * 96 + ch * 8);
    }
    __syncthreads();
    for (int v = t; v < 96 * 12; v += 256) {
        int r = v / 12, ch = v - r * 12;
        ushort8 o;
#pragma unroll
        for (int kk = 0; kk < 8; ++kk) o[kk] = T[ch * 8 + kk][r];
        *(ushort8*)(om + r * 96 + ch * 8) = o;
    }
}

// ---------------- scores (both orientations): grid (96, 2, g) ----------------
// ori=0 (HT): att[h,s,j] = sum_c qT[c,s,h]*kT[c,s,j], mask j==h
// ori=1 (W) : att[s,w,96+j] = sum_c q[c,s,w]*k[c,s,j]
__global__ __launch_bounds__(256) void scores_kernel(
    const float* __restrict__ qT, const float* __restrict__ kT,
    const float* __restrict__ q, const float* __restrict__ k,
    float* __restrict__ att)
{
    int s = blockIdx.x;
    int ori = blockIdx.y;
    size_t b = blockIdx.z;
    const float* qs = (ori ? q : qT) + b * (size_t)C8P;
    const float* ks = (ori ? k : kT) + b * (size_t)C8P;
    float* attb = att + b * (size_t)ATTN;

    __shared__ __align__(16) float Qs[64][96];
    __shared__ __align__(16) float Ks[64][96];
    int t = threadIdx.x;
    for (int v = t; v < 64 * 24; v += 256) {
        int c = v / 24, ch = v - c * 24;
        size_t gi = (size_t)c * PP + (size_t)s * 96 + ch * 4;
        *(float4*)&Qs[c][ch * 4] = *(const float4*)(qs + gi);
        *(float4*)&Ks[c][ch * 4] = *(const float4*)(ks + gi);
    }
    __syncthreads();
    int tx = t & 15, ty = t >> 4;
    float acc[6][6] = {};
    for (int c = 0; c < 64; ++c) {
        float qf[6], kf[6];
#pragma unroll
        for (int i = 0; i < 6; ++i) { qf[i] = Qs[c][ty + 16 * i]; kf[i] = Ks[c][tx + 16 * i]; }
#pragma unroll
        for (int i = 0; i < 6; ++i)
#pragma unroll
            for (int j = 0; j < 6; ++j) acc[i][j] = fmaf(qf[i], kf[j], acc[i][j]);
    }
    if (ori == 0) {
#pragma unroll
        for (int i = 0; i < 6; ++i) {
            int h = ty + 16 * i;
#pragma unroll
            for (int j = 0; j < 6; ++j) {
                int jj = tx + 16 * j;
                attb[((size_t)h * 96 + s) * 192 + jj] = (jj == h) ? -INFINITY : acc[i][j];
            }
        }
    } else {
#pragma unroll
        for (int i = 0; i < 6; ++i) {
            int w = ty + 16 * i;
#pragma unroll
            for (int j = 0; j < 6; ++j) {
                int jj = tx + 16 * j;
                attb[((size_t)s * 96 + w) * 192 + 96 + jj] = acc[i][j];
            }
        }
    }
}

// ---------------- softmax over 192: 48 lanes x float4, fp32 in -> bf16 out ----------------
__global__ __launch_bounds__(256) void softmax192_kernel(
    const float* __restrict__ att, unsigned short* __restrict__ attb, int nrows)
{
    int row = blockIdx.x * 4 + (threadIdx.x >> 6);
    int lane = threadIdx.x & 63;
    if (row >= nrows) return;
    const float* r = att + (size_t)row * 192;
    unsigned short* o = attb + (size_t)row * 192;
    float4 v = { -INFINITY, -INFINITY, -INFINITY, -INFINITY };
    if (lane < 48) v = *(const float4*)(r + lane * 4);
    float m = fmaxf(fmaxf(v.x, v.y), fmaxf(v.z, v.w));
#pragma unroll
    for (int off = 32; off; off >>= 1) m = fmaxf(m, __shfl_xor(m, off));
    float e0 = __expf(v.x - m), e1 = __expf(v.y - m), e2 = __expf(v.z - m), e3 = __expf(v.w - m);
    float s = (lane < 48) ? (e0 + e1 + e2 + e3) : 0.0f;
#pragma unroll
    for (int off = 32; off; off >>= 1) s += __shfl_xor(s, off);
    float inv = 1.0f / s;
    if (lane < 48) {
        ushort4v ov = { f2bf(e0 * inv), f2bf(e1 * inv), f2bf(e2 * inv), f2bf(e3 * inv) };
        *(ushort4v*)(o + lane * 4) = ov;
    }
}

// ---------------- MFMA apply, both orientations + both c-tiles: grid (96, 4, g), 512 thr ----------------
// y = (ori<<1)|ct ; ori=0: rawHT[c,s,h] = sum_j att[h,s,j]*vT[c,s,j]
//                   ori=1: rawW [c,s,w] = sum_j att[s,w,96+j]*v[c,s,j]
__global__ __launch_bounds__(512) void apply_mfma(
    const unsigned short* __restrict__ v, const unsigned short* __restrict__ vT,
    const unsigned short* __restrict__ att,
    unsigned short* __restrict__ rawHT, unsigned short* __restrict__ rawW)
{
    int s = blockIdx.x;
    int yy = blockIdx.y;
    int ct = yy & 1, ori = yy >> 1;
    int c0 = ct * 256;
    size_t b = blockIdx.z;
    const unsigned short* vb = (ori ? v : vT) + b * (size_t)CP;
    const unsigned short* ab = att + b * (size_t)ATTN;
    unsigned short* ob = (ori ? rawW : rawHT) + b * (size_t)CP;

    __shared__ __align__(16) unsigned short Asm[256][104];
    __shared__ __align__(16) unsigned short Bsm[96][104];

    int tid = threadIdx.x;
    {
        int r = tid >> 1, half = tid & 1;
        const unsigned short* src = vb + (size_t)(c0 + r) * PP + s * 96 + half * 48;
#pragma unroll
        for (int i = 0; i < 6; ++i)
            *(ushort8*)&Asm[r][half * 48 + i * 8] = *(const ushort8*)(src + i * 8);
    }
    if (tid < 192) {
        int r = tid >> 1, half = tid & 1;
        size_t base = ori ? ((size_t)(s * 96 + r) * 192 + 96)
                          : ((size_t)(r * 96 + s) * 192);
        const unsigned short* src = ab + base + half * 48;
#pragma unroll
        for (int i = 0; i < 6; ++i)
            *(ushort8*)&Bsm[r][half * 48 + i * 8] = *(const ushort8*)(src + i * 8);
    }
    __syncthreads();

    int lane = tid & 63, wid = tid >> 6;
    int wr = wid >> 1, wc = wid & 1;
    int l15 = lane & 15, l4 = lane >> 4;
    f32x4 acc[4][3] = {};
#pragma unroll
    for (int k = 0; k < 3; ++k) {
        bf16x8 a[4], bb[3];
#pragma unroll
        for (int m = 0; m < 4; ++m)
            a[m] = *(const bf16x8*)&Asm[wr * 64 + m * 16 + l15][k * 32 + l4 * 8];
#pragma unroll
        for (int n = 0; n < 3; ++n)
            bb[n] = *(const bf16x8*)&Bsm[wc * 48 + n * 16 + l15][k * 32 + l4 * 8];
#pragma unroll
        for (int m = 0; m < 4; ++m)
#pragma unroll
            for (int n = 0; n < 3; ++n)
                acc[m][n] = __builtin_amdgcn_mfma_f32_16x16x32_bf16(a[m], bb[n], acc[m][n], 0, 0, 0);
    }
#pragma unroll
    for (int m = 0; m < 4; ++m)
#pragma unroll
        for (int n = 0; n < 3; ++n) {
            int col = wc * 48 + n * 16 + l15;
#pragma unroll
            for (int r = 0; r < 4; ++r) {
                int crow = c0 + wr * 64 + m * 16 + l4 * 4 + r;
                ob[(size_t)crow * PP + s * 96 + col] = f2bf(acc[m][n][r]);
            }
        }
}

// ---------------- combine, vectorized: out[c,h,w] = g*(rawHT[c,w,h]+rawW[c,h,w]+2)+x ----------------
__global__ __launch_bounds__(256) void combine_b(
    const unsigned short* __restrict__ rawHT, const unsigned short* __restrict__ rawW,
    const float* __restrict__ x, const float* __restrict__ gamma,
    float* __restrict__ out)
{
    size_t m = blockIdx.x;
    const unsigned short* a  = rawHT + m * (size_t)PP;
    const unsigned short* bw = rawW  + m * (size_t)PP;
    const float* xm = x + m * (size_t)PP;
    float* om = out + m * (size_t)PP;
    float g = gamma[0];
    __shared__ __align__(16) unsigned short T[96][104];
    int t = threadIdx.x;
    for (int v = t; v < 96 * 12; v += 256) {
        int r = v / 12, ch = v - r * 12;
        *(ushort8*)&T[r][ch * 8] = *(const ushort8*)(a + r * 96 + ch * 8);
    }
    __syncthreads();
    for (int v = t; v < 96 * 24; v += 256) {
        int r = v / 24, ch = v - r * 24;          // r = h, cols = ch*4..+3 (w)
        float4 x4 = *(const float4*)(xm + r * 96 + ch * 4);
        ushort4v w4 = *(const ushort4v*)(bw + r * 96 + ch * 4);
        float4 o;
        o.x = g * (bf2f(T[ch * 4 + 0][r]) + bf2f(w4.x) + 2.0f) + x4.x;
        o.y = g * (bf2f(T[ch * 4 + 1][r]) + bf2f(w4.y) + 2.0f) + x4.y;
        o.z = g * (bf2f(T[ch * 4 + 2][r]) + bf2f(w4.z) + 2.0f) + x4.z;
        o.w = g * (bf2f(T[ch * 4 + 3][r]) + bf2f(w4.w) + 2.0f) + x4.w;
        *(float4*)(om + r * 96 + ch * 4) = o;
    }
}

extern "C" void kernel_launch(void* const* d_in, const int* in_sizes, int n_in,
                              void* d_out, int out_size, void* d_ws, size_t ws_size,
                              hipStream_t stream)
{
    const float* x_ex = (const float*)d_in[0];
    const float* x_q  = (const float*)d_in[1];
    const float* Wq   = (const float*)d_in[2];
    const float* bq   = (const float*)d_in[3];
    const float* Wk   = (const float*)d_in[4];
    const float* bk   = (const float*)d_in[5];
    const float* Wv   = (const float*)d_in[6];
    const float* bv   = (const float*)d_in[7];
    const float* Wqv  = (const float*)d_in[8];
    const float* bqv  = (const float*)d_in[9];
    const float* g1   = (const float*)d_in[10];
    const float* g2   = (const float*)d_in[11];
    float* out0 = (float*)d_out;
    float* out1 = out0 + (size_t)8 * CP;

    char* p = (char*)d_ws;
    unsigned short* Wvb  = (unsigned short*)p; p += (size_t)262144 * 2;
    unsigned short* Wqvb = (unsigned short*)p; p += (size_t)262144 * 2;
    unsigned short* Wqb  = (unsigned short*)p; p += (size_t)32768 * 2;
    unsigned short* Wkb  = (unsigned short*)p; p += (size_t)32768 * 2;

    size_t per = (size_t)ATTN * 4 + (size_t)ATTN * 2 + 6ull * CP * 2 + 4ull * C8P * 4;
    size_t head = (size_t)(p - (char*)d_ws);
    int g = 8;
    while (g > 1 && head + (size_t)g * per > ws_size) g >>= 1;

    char* q = p;
    float*          attf = (float*)q;          q += (size_t)g * ATTN * 4;
    unsigned short* attb = (unsigned short*)q; q += (size_t)g * ATTN * 2;
    unsigned short* xTe  = (unsigned short*)q; q += (size_t)g * CP * 2;
    unsigned short* xTq  = (unsigned short*)q; q += (size_t)g * CP * 2;
    unsigned short* vbuf = (unsigned short*)q; q += (size_t)g * CP * 2;
    unsigned short* vTb  = (unsigned short*)q; q += (size_t)g * CP * 2;
    unsigned short* raw1 = (unsigned short*)q; q += (size_t)g * CP * 2;
    unsigned short* raw2 = (unsigned short*)q; q += (size_t)g * CP * 2;
    float* qbuf  = (float*)q; q += (size_t)g * C8P * 4;
    float* kbuf  = (float*)q; q += (size_t)g * C8P * 4;
    float* qTbuf = (float*)q; q += (size_t)g * C8P * 4;
    float* kTbuf = (float*)q; q += (size_t)g * C8P * 4;

    cast_w<<<dim3(256, 4), 256, 0, stream>>>(Wv, Wqv, Wq, Wk, Wvb, Wqvb, Wqb, Wkb);

    for (int b0 = 0; b0 < 8; b0 += g) {
        const float* xe = x_ex + (size_t)b0 * CP;
        const float* xq = x_q  + (size_t)b0 * CP;
        float* o0 = out0 + (size_t)b0 * CP;
        float* o1 = out1 + (size_t)b0 * CP;

        cast_transpose_cp<<<dim3(144, 8, 2 * g), 256, 0, stream>>>(xq, xe, xTq, xTe);
        gemm_qk<<<dim3(72, 2, g), 256, 0, stream>>>(Wqb, Wkb, xTq, xTe, bq, bk, qbuf, kbuf);
        transpose_hw_qk<<<dim3(2 * g * 64), 256, 0, stream>>>(qbuf, kbuf, qTbuf, kTbuf, g * 64);
        scores_kernel<<<dim3(96, 2, g), 256, 0, stream>>>(qTbuf, kTbuf, qbuf, kbuf, attf);
        int rows = g * PP;
        softmax192_kernel<<<dim3(rows / 4), 256, 0, stream>>>(attf, attb, rows);

        // examplar path
        gemm_v<<<dim3(72, 4, g), 256, 0, stream>>>(Wvb, xTe, bv, vbuf);
        transpose_hw_b<<<dim3(g * 512), 256, 0, stream>>>(vbuf, vTb);
        apply_mfma<<<dim3(96, 4, g), 512, 0, stream>>>(vbuf, vTb, attb, raw1, raw2);
        combine_b<<<dim3(g * 512), 256, 0, stream>>>(raw1, raw2, xe, g1, o0);

        // query path
        gemm_v<<<dim3(72, 4, g), 256, 0, stream>>>(Wqvb, xTq, bqv, vbuf);
        transpose_hw_b<<<dim3(g * 512), 256, 0, stream>>>(vbuf, vTb);
        apply_mfma<<<dim3(96, 4, g), 512, 0, stream>>>(vbuf, vTb, attb, raw1, raw2);
        combine_b<<<dim3(g * 512), 256, 0, stream>>>(raw1, raw2, xq, g2, o1);
    }
}